// Round 15
// baseline (237.826 us; speedup 1.0000x reference)
//
#include <hip/hip_runtime.h>
#include <hip/hip_bf16.h>

#define HEADS 16
#define DH    64
#define BATCH 4
#define SEQ   1024
#define DIMD  1024
#define TOK   4096

typedef __attribute__((ext_vector_type(8))) short bf16x8;
typedef __attribute__((ext_vector_type(4))) float f32x4;
typedef __attribute__((ext_vector_type(16))) float f32x16;

typedef const void __attribute__((address_space(1)))* gas1_t;
typedef void __attribute__((address_space(3)))* las3_t;

#define GLOAD16(g,l) __builtin_amdgcn_global_load_lds((gas1_t)(g),(las3_t)(l),16,0,0)
#define MFMA_BF16(a,b,c) __builtin_amdgcn_mfma_f32_16x16x32_bf16((a),(b),(c),0,0,0)
#define MFMA32(a,b,c) __builtin_amdgcn_mfma_f32_32x32x16_bf16((a),(b),(c),0,0,0)
#define ZERO16 {0.f,0.f,0.f,0.f,0.f,0.f,0.f,0.f,0.f,0.f,0.f,0.f,0.f,0.f,0.f,0.f}

__device__ __forceinline__ ushort f2bf(float f){
  __hip_bfloat16 h = __float2bfloat16(f);
  return *reinterpret_cast<ushort*>(&h);
}
__device__ __forceinline__ uint packbf2(float a, float b){
  return (uint)f2bf(a) | ((uint)f2bf(b) << 16);
}
__device__ __forceinline__ uint xswap32(uint x){   // lane l <-> lane l^32
  return (uint)__shfl_xor((int)x, 32);
}

// ------------- merged prep: cast_x | norm_rows(wq,wk,wv) | cast_wo | wo_part -------------
__global__ __launch_bounds__(256) void prep_kernel(
    const float* __restrict__ x,
    const float* __restrict__ wq, const float* __restrict__ wk, const float* __restrict__ wv,
    const float* __restrict__ wo,
    ushort* __restrict__ xb,
    ushort* __restrict__ oq, ushort* __restrict__ ok, ushort* __restrict__ ov,
    ushort* __restrict__ wob, float* __restrict__ part)
{
  __shared__ float sp[4];
  int bid = blockIdx.x, t = threadIdx.x;
  if (bid < 2048){
    int i = bid*256 + t;
    const float4* x4 = (const float4*)x;
    float4 a = x4[2*i], b = x4[2*i+1];
    union { ushort s[8]; uint4 u; } uu;
    uu.s[0]=f2bf(a.x); uu.s[1]=f2bf(a.y); uu.s[2]=f2bf(a.z); uu.s[3]=f2bf(a.w);
    uu.s[4]=f2bf(b.x); uu.s[5]=f2bf(b.y); uu.s[6]=f2bf(b.z); uu.s[7]=f2bf(b.w);
    ((uint4*)xb)[i] = uu.u;
  } else if (bid < 5120){
    int bb = bid - 2048;
    int row = bb & 1023;
    int m = bb >> 10;
    const float* src = (m==0)?wq:((m==1)?wk:wv);
    ushort* dst = (m==0)?oq:((m==1)?ok:ov);
    float4 v = ((const float4*)(src + (size_t)row*1024))[t];
    float sc = (t<128)?2.f:1.f;
    float ss = sc*sc*(v.x*v.x + v.y*v.y + v.z*v.z + v.w*v.w);
    #pragma unroll
    for (int off=1; off<64; off<<=1) ss += __shfl_xor(ss, off);
    int w = t>>6, lane = t&63;
    if (lane==0) sp[w]=ss;
    __syncthreads();
    float tot = sp[0]+sp[1]+sp[2]+sp[3];
    float inv = rsqrtf(fmaxf(tot,1e-20f)) * sc;
    union { ushort s[4]; uint2 u; } o;
    o.s[0]=f2bf(v.x*inv); o.s[1]=f2bf(v.y*inv); o.s[2]=f2bf(v.z*inv); o.s[3]=f2bf(v.w*inv);
    ((uint2*)(dst + (size_t)row*1024))[t] = o.u;
  } else if (bid < 5632){
    int i = (bid-5120)*256 + t;
    float sc = ((i>>7) < 512) ? 2.f : 1.f;
    const float4* x4 = (const float4*)wo;
    float4 a = x4[2*i], b = x4[2*i+1];
    union { ushort s[8]; uint4 u; } uu;
    uu.s[0]=f2bf(a.x*sc); uu.s[1]=f2bf(a.y*sc); uu.s[2]=f2bf(a.z*sc); uu.s[3]=f2bf(a.w*sc);
    uu.s[4]=f2bf(b.x*sc); uu.s[5]=f2bf(b.y*sc); uu.s[6]=f2bf(b.z*sc); uu.s[7]=f2bf(b.w*sc);
    ((uint4*)wob)[i] = uu.u;
  } else {
    int rb = bid - 5632;
    float4 a = {0.f,0.f,0.f,0.f};
    #pragma unroll 4
    for (int r=0;r<32;r++){
      int row = rb*32+r;
      float4 v = ((const float4*)wo)[row*256 + t];
      float s2 = (row<512)?4.f:1.f;
      a.x += s2*v.x*v.x; a.y += s2*v.y*v.y; a.z += s2*v.z*v.z; a.w += s2*v.w*v.w;
    }
    ((float4*)part)[rb*256 + t] = a;
  }
}

__global__ __launch_bounds__(256) void wo_csum_kernel(const float* __restrict__ part,
                                                      float* __restrict__ colsum){
  int c = blockIdx.x*256 + threadIdx.x;
  float s = 0.f;
  #pragma unroll
  for (int j=0;j<32;j++) s += part[j*1024 + c];
  colsum[c] = s;
}

// ------------- fused 64x128 B^T GEMM, BK=32, counted-vmcnt 2-phase pipeline ----
// stage(next) issued BEFORE compute; wait is vmcnt(LOADS) = only the PREVIOUS
// tile's loads (issued one compute-phase ago) -> next tile's 7 loads stay in
// flight across the MFMA phase. Raw s_barrier (no implicit vmcnt(0) drain).
// Buffer-reuse safety: stage(bufX) only issued after the barrier ending the
// compute that read bufX.
// NZ=3: z=0 q [bh][n][d] head-norm + chan scale(incl log2e); z=1 k head-norm;
//       z=2 v TRANSPOSED [bh][d][n], colsum folded.   NZ=1: fp32 out to dst0.
template<int NZ>
__global__ __launch_bounds__(256, 2) void gemm_fused_kernel(
    const ushort* __restrict__ A,
    const ushort* __restrict__ B0, const ushort* __restrict__ B1, const ushort* __restrict__ B2,
    void* dst0, void* dst1, void* dst2,
    const float* __restrict__ qparam, const float* __restrict__ colsum, int K)
{
  __shared__ ushort As[2][2048];          // 2 x 4KB
  __shared__ ushort Bs[2][NZ*4096];       // 2 x NZ x 8KB
  const int bm = blockIdx.x*64, bn = blockIdx.y*128;
  const int tid = threadIdx.x, lane = tid&63, w = tid>>6;
  const int wr = w>>1, wc = w&1;
  const int l15 = lane&15, l4 = lane>>4;
  const int srow = lane>>2, sch = lane&3;
  const int scol = (sch ^ (srow&3))*8;      // swizzled source chunk (ushorts)

  const f32x4 zero4 = {0.f,0.f,0.f,0.f};
  f32x4 acc[NZ][2][4];
  #pragma unroll
  for (int z=0;z<NZ;z++)
    #pragma unroll
    for (int m=0;m<2;m++)
      #pragma unroll
      for (int n=0;n<4;n++) acc[z][m][n] = zero4;

  auto stage = [&](int c, int k0){
    GLOAD16(A + (size_t)(bm + w*16 + srow)*K + k0 + scol, &As[c][w*512]);
    #pragma unroll
    for (int j=0;j<NZ*2;j++){
      int seg = j*4 + w;
      int z = seg>>3, s = seg&7;
      const ushort* Bp = (z==0)?B0:((z==1)?B1:B2);
      GLOAD16(Bp + (size_t)(bn + s*16 + srow)*K + k0 + scol, &Bs[c][seg*512]);
    }
  };
  auto compute = [&](int c){
    bf16x8 af[2];
    #pragma unroll
    for (int m=0;m<2;m++)
      af[m] = *(const bf16x8*)&As[c][(wr*32 + m*16 + l15)*32 + ((l4 ^ (l15&3))*8)];
    #pragma unroll
    for (int z=0;z<NZ;z++){
      bf16x8 bfr[4];
      #pragma unroll
      for (int n=0;n<4;n++)
        bfr[n] = *(const bf16x8*)&Bs[c][z*4096 + (wc*64 + n*16 + l15)*32 + ((l4 ^ (l15&3))*8)];
      #pragma unroll
      for (int m=0;m<2;m++)
        #pragma unroll
        for (int n=0;n<4;n++)
          acc[z][m][n] = MFMA_BF16(af[m], bfr[n], acc[z][m][n]);
    }
  };

  stage(0, 0);
  asm volatile("s_waitcnt vmcnt(0)" ::: "memory");
  __builtin_amdgcn_s_barrier();
  int cur = 0;
  for (int k0=32; k0<K; k0+=32){
    stage(cur^1, k0);                 // issue next tile (stays in flight over MFMA)
    if (NZ==3) asm volatile("s_waitcnt vmcnt(7)" ::: "memory");  // prev tile done
    else       asm volatile("s_waitcnt vmcnt(3)" ::: "memory");
    __builtin_amdgcn_s_barrier();     // all waves' cur-tile segs landed
    compute(cur);
    __builtin_amdgcn_s_barrier();     // all done reading cur before next overwrite
    cur ^= 1;
  }
  asm volatile("s_waitcnt vmcnt(0)" ::: "memory");
  __builtin_amdgcn_s_barrier();
  compute(cur);

  if (NZ==3){
    #pragma unroll
    for (int z=0;z<3;z++){
      ushort* dst = (ushort*)((z==0)?dst0:((z==1)?dst1:dst2));
      float qs[4];
      #pragma unroll
      for (int n=0;n<4;n++){
        int e = bn + wc*64 + n*16 + l15;
        if (z==0)      qs[n] = qparam[e]*8192.f*1.44269504088896f;
        else if (z==2) qs[n] = rsqrtf(fmaxf(colsum[e],1e-20f));
        else           qs[n] = 1.f;
      }
      #pragma unroll
      for (int m=0;m<2;m++){
        float ssq[4] = {0.f,0.f,0.f,0.f};
        if (z<2){
          #pragma unroll
          for (int reg=0;reg<4;reg++){
            float s=0.f;
            #pragma unroll
            for (int n=0;n<4;n++){
              float scl2 = (n<2)?4.f:1.f;
              float vv = acc[z][m][n][reg];
              s += scl2*vv*vv;
            }
            ssq[reg]=s;
          }
          #pragma unroll
          for (int d=1; d<16; d<<=1){
            #pragma unroll
            for (int reg=0;reg<4;reg++) ssq[reg] += __shfl_xor(ssq[reg], d);
          }
        }
        #pragma unroll
        for (int n=0;n<4;n++){
          float scl = (n<2)?2.f:1.f;
          #pragma unroll
          for (int reg=0;reg<4;reg++){
            float val = acc[z][m][n][reg];
            if (z<2) val = val*scl*rsqrtf(fmaxf(ssq[reg],1e-20f))*qs[n];
            else     val = val*qs[n];
            int row = bm + wr*32 + m*16 + l4*4 + reg;
            int col = bn + wc*64 + n*16 + l15;
            int b = row>>10, nn = row&1023, h = col>>6, d = col&63;
            if (z==2)
              dst[(((size_t)b*HEADS+h)*DH + d)*SEQ + nn] = f2bf(val);     // V^T
            else
              dst[(((size_t)b*HEADS+h)*SEQ + nn)*DH + d] = f2bf(val);
          }
        }
      }
    }
  } else {
    float* outp = (float*)dst0;
    #pragma unroll
    for (int m=0;m<2;m++)
      #pragma unroll
      for (int n=0;n<4;n++)
        #pragma unroll
        for (int reg=0;reg<4;reg++){
          int row = bm + wr*32 + m*16 + l4*4 + reg;
          int col = bn + wc*64 + n*16 + l15;
          outp[(size_t)row*DIMD + col] = acc[0][m][n][reg];
        }
  }
}

// ------------- attention: 32x32 swapped-QK^T, shfl_xor(32) cross-lane -------------
template<int NS, bool MASK>
__device__ __forceinline__ void attn_iter(
    const ushort* __restrict__ Kp, const ushort* __restrict__ Vp,
    int kvb, const bf16x8 (&qf)[4], int l31, int l1,
    f32x16& o0, f32x16& o1, float& m_s, float& l_s)
{
  // ---- loads up front ----
  bf16x8 kfa[4], kfb[4];
  #pragma unroll
  for (int md=0; md<4; md++)
    kfa[md] = *(const bf16x8*)&Kp[(size_t)(kvb + l31)*DH + md*16 + l1*8];
  if (NS==2){
    #pragma unroll
    for (int md=0; md<4; md++)
      kfb[md] = *(const bf16x8*)&Kp[(size_t)(kvb + 32 + l31)*DH + md*16 + l1*8];
  }
  bf16x8 vf0[2*NS], vf1[2*NS];
  #pragma unroll
  for (int kc=0; kc<2*NS; kc++){
    vf0[kc] = *(const bf16x8*)&Vp[(size_t)l31*SEQ      + kvb + kc*16 + l1*8];
    vf1[kc] = *(const bf16x8*)&Vp[(size_t)(32+l31)*SEQ + kvb + kc*16 + l1*8];
  }

  // ---- S^T ----
  f32x16 s0 = ZERO16, s1 = ZERO16;
  __builtin_amdgcn_s_setprio(1);
  #pragma unroll
  for (int md=0; md<4; md++) s0 = MFMA32(kfa[md], qf[md], s0);
  if (NS==2){
    #pragma unroll
    for (int md=0; md<4; md++) s1 = MFMA32(kfb[md], qf[md], s1);
  }
  __builtin_amdgcn_s_setprio(0);

  if (MASK){
    f32x16& sm = (NS==2) ? s1 : s0;
    #pragma unroll
    for (int r=0;r<16;r++){
      int kvl = (r&3) + 8*(r>>2) + 4*l1;
      if (kvl > l31) sm[r] = -3.0e38f;
    }
  }

  // ---- online softmax (log2 domain), lane-local + shfl_xor(32) combine ----
  float mx = -3.0e38f;
  #pragma unroll
  for (int r=0;r<16;r++) mx = fmaxf(mx, s0[r]);
  if (NS==2){
    #pragma unroll
    for (int r=0;r<16;r++) mx = fmaxf(mx, s1[r]);
  }
  mx = fmaxf(mx, __shfl_xor(mx, 32));
  float mnew = fmaxf(m_s, mx);
  float alpha = __builtin_amdgcn_exp2f(m_s - mnew);
  m_s = mnew;
  float rs = 0.f;
  #pragma unroll
  for (int r=0;r<16;r++){ s0[r] = __builtin_amdgcn_exp2f(s0[r]-mnew); rs += s0[r]; }
  if (NS==2){
    #pragma unroll
    for (int r=0;r<16;r++){ s1[r] = __builtin_amdgcn_exp2f(s1[r]-mnew); rs += s1[r]; }
  }
  rs += __shfl_xor(rs, 32);
  l_s = l_s*alpha + rs;

  // ---- rescale O ----
  #pragma unroll
  for (int r=0;r<16;r++){ o0[r] *= alpha; o1[r] *= alpha; }

  // ---- P -> bf16 pairs; shfl_xor(32) + select builds B-fragments ----
  uint ru[16];
  #pragma unroll
  for (int j=0;j<8;j++) ru[j] = packbf2(s0[2*j], s0[2*j+1]);
  if (NS==2){
    #pragma unroll
    for (int j=0;j<8;j++) ru[8+j] = packbf2(s1[2*j], s1[2*j+1]);
  }
  union U4 { uint u[4]; bf16x8 v; };
  U4 fr[2*NS];
  #pragma unroll
  for (int j=0;j<NS;j++){
    uint px[8];
    #pragma unroll
    for (int k=0;k<8;k++) px[k] = xswap32(ru[8*j+k]);
    fr[2*j].u[0]   = l1 ? px[2]      : ru[8*j+0];
    fr[2*j].u[1]   = l1 ? px[3]      : ru[8*j+1];
    fr[2*j].u[2]   = l1 ? ru[8*j+2]  : px[0];
    fr[2*j].u[3]   = l1 ? ru[8*j+3]  : px[1];
    fr[2*j+1].u[0] = l1 ? px[6]      : ru[8*j+4];
    fr[2*j+1].u[1] = l1 ? px[7]      : ru[8*j+5];
    fr[2*j+1].u[2] = l1 ? ru[8*j+6]  : px[4];
    fr[2*j+1].u[3] = l1 ? ru[8*j+7]  : px[5];
  }

  // ---- PV: O^T[d][q] += V^T fragments x P ----
  __builtin_amdgcn_s_setprio(1);
  #pragma unroll
  for (int kc=0; kc<2*NS; kc++){
    o0 = MFMA32(vf0[kc], fr[kc].v, o0);
    o1 = MFMA32(vf1[kc], fr[kc].v, o1);
  }
  __builtin_amdgcn_s_setprio(0);
}

__device__ __forceinline__ void process_tile(
    int t, int par, int bh,
    const ushort* __restrict__ Q, const ushort* __restrict__ K,
    const ushort* __restrict__ VT, ushort* __restrict__ O,
    int l31, int l1)
{
  const size_t base  = (size_t)bh * SEQ * DH;
  const size_t vbase = (size_t)bh * DH * SEQ;
  const ushort* Kp = K + base;
  const ushort* Vp = VT + vbase;
  const int qbase = t*64 + par*32;

  bf16x8 qf[4];
  #pragma unroll
  for (int md=0; md<4; md++)
    qf[md] = *(const bf16x8*)&Q[base + (size_t)(qbase + l31)*DH + md*16 + l1*8];

  f32x16 o0 = ZERO16, o1 = ZERO16;
  float m_s = -3.0e38f, l_s = 0.f;

  for (int kt=0; kt<t; kt++)
    attn_iter<2,false>(Kp, Vp, kt*64, qf, l31, l1, o0, o1, m_s, l_s);
  if (par) attn_iter<2,true>(Kp, Vp, t*64, qf, l31, l1, o0, o1, m_s, l_s);
  else     attn_iter<1,true>(Kp, Vp, t*64, qf, l31, l1, o0, o1, m_s, l_s);

  float li = 1.0f / l_s;
  int b = bh >> 4, hh = bh & 15;
  int n = qbase + l31;
  ushort* orow = O + ((size_t)b*SEQ + n)*DIMD + hh*64;
  #pragma unroll
  for (int r=0;r<16;r++){
    int dl = (r&3) + 8*(r>>2) + 4*l1;
    orow[dl]    = f2bf(o0[r]*li);
    orow[32+dl] = f2bf(o1[r]*li);
  }
}

__global__ __launch_bounds__(256, 2) void attn_kernel(
    const ushort* __restrict__ Q, const ushort* __restrict__ K, const ushort* __restrict__ VT,
    ushort* __restrict__ O)
{
  int id = blockIdx.x;                  // 512 blocks
  int p  = id >> 6;                     // pair index 0..7 -> tiles {p, 15-p}
  int r  = id & 63;
  int bh = (r&7)*8 + (r>>3);            // XCD x serves bh in [8x, 8x+8)
  int tid = threadIdx.x, wi = tid>>6, lane = tid&63;
  int l31 = lane & 31, l1 = lane >> 5;
  int sel = (wi & 1) ^ (bh & 1);        // balance SIMD load across co-resident blocks
  int t   = sel ? (15-p) : p;
  int par = wi >> 1;
  process_tile(t, par, bh, Q, K, VT, O, l31, l1);
}

extern "C" void kernel_launch(void* const* d_in, const int* in_sizes, int n_in,
                              void* d_out, int out_size, void* d_ws, size_t ws_size,
                              hipStream_t stream)
{
  const float* x      = (const float*)d_in[0];
  const float* w_q    = (const float*)d_in[1];
  const float* w_k    = (const float*)d_in[2];
  const float* w_v    = (const float*)d_in[3];
  const float* w_o    = (const float*)d_in[4];
  const float* qparam = (const float*)d_in[5];
  char* ws = (char*)d_ws;
  const size_t MB = 1u<<20;
  ushort* xb  = (ushort*)(ws);             // 8MB; reused as attention output
  ushort* wqb = (ushort*)(ws + 8*MB);      // 2MB each
  ushort* wkb = (ushort*)(ws + 10*MB);
  ushort* wvb = (ushort*)(ws + 12*MB);
  ushort* wob = (ushort*)(ws + 14*MB);
  ushort* qd  = (ushort*)(ws + 16*MB);     // 8MB each
  ushort* kd  = (ushort*)(ws + 24*MB);
  ushort* vd  = (ushort*)(ws + 32*MB);     // V^T [bh][d][n], wo-colsum folded
  ushort* att = xb;
  float* part = (float*)(ws + 40*MB);      // 128KB scratch
  float* colsum = (float*)d_out + (out_size - 1024);  // overwritten by final GEMM

  prep_kernel<<<dim3(5664), dim3(256), 0, stream>>>(
      x, w_q, w_k, w_v, w_o, xb, wqb, wkb, wvb, wob, part);
  wo_csum_kernel<<<dim3(4), dim3(256), 0, stream>>>(part, colsum);
  gemm_fused_kernel<3><<<dim3(64,8), dim3(256), 0, stream>>>(
      xb, wqb, wkb, wvb, (void*)qd, (void*)kd, (void*)vd, qparam, colsum, DIMD);
  attn_kernel<<<dim3(512), dim3(256), 0, stream>>>(qd, kd, vd, att);
  gemm_fused_kernel<1><<<dim3(64,8), dim3(256), 0, stream>>>(
      att, wob, wob, wob, d_out, nullptr, nullptr, nullptr, nullptr, DIMD);
}

// Round 16
// 120.268 us; speedup vs baseline: 1.9775x; 1.9775x over previous
//
#include <hip/hip_runtime.h>
#include <hip/hip_bf16.h>

#define HEADS 16
#define DH    64
#define BATCH 4
#define SEQ   1024
#define DIMD  1024
#define TOK   4096

typedef __attribute__((ext_vector_type(8))) short bf16x8;
typedef __attribute__((ext_vector_type(4))) float f32x4;
typedef __attribute__((ext_vector_type(16))) float f32x16;

typedef const void __attribute__((address_space(1)))* gas1_t;
typedef void __attribute__((address_space(3)))* las3_t;

#define GLOAD16(g,l) __builtin_amdgcn_global_load_lds((gas1_t)(g),(las3_t)(l),16,0,0)
#define MFMA_BF16(a,b,c) __builtin_amdgcn_mfma_f32_16x16x32_bf16((a),(b),(c),0,0,0)
#define MFMA32(a,b,c) __builtin_amdgcn_mfma_f32_32x32x16_bf16((a),(b),(c),0,0,0)
#define ZERO16 {0.f,0.f,0.f,0.f,0.f,0.f,0.f,0.f,0.f,0.f,0.f,0.f,0.f,0.f,0.f,0.f}

__device__ __forceinline__ ushort f2bf(float f){
  __hip_bfloat16 h = __float2bfloat16(f);
  return *reinterpret_cast<ushort*>(&h);
}
__device__ __forceinline__ uint packbf2(float a, float b){
  return (uint)f2bf(a) | ((uint)f2bf(b) << 16);
}
__device__ __forceinline__ uint xswap32(uint x){   // lane l <-> lane l^32
  return (uint)__shfl_xor((int)x, 32);
}

// ------------- merged prep: cast_x | norm_rows(wq,wk,wv) | cast_wo | wo_part -------------
__global__ __launch_bounds__(256) void prep_kernel(
    const float* __restrict__ x,
    const float* __restrict__ wq, const float* __restrict__ wk, const float* __restrict__ wv,
    const float* __restrict__ wo,
    ushort* __restrict__ xb,
    ushort* __restrict__ oq, ushort* __restrict__ ok, ushort* __restrict__ ov,
    ushort* __restrict__ wob, float* __restrict__ part)
{
  __shared__ float sp[4];
  int bid = blockIdx.x, t = threadIdx.x;
  if (bid < 2048){
    int i = bid*256 + t;
    const float4* x4 = (const float4*)x;
    float4 a = x4[2*i], b = x4[2*i+1];
    union { ushort s[8]; uint4 u; } uu;
    uu.s[0]=f2bf(a.x); uu.s[1]=f2bf(a.y); uu.s[2]=f2bf(a.z); uu.s[3]=f2bf(a.w);
    uu.s[4]=f2bf(b.x); uu.s[5]=f2bf(b.y); uu.s[6]=f2bf(b.z); uu.s[7]=f2bf(b.w);
    ((uint4*)xb)[i] = uu.u;
  } else if (bid < 5120){
    int bb = bid - 2048;
    int row = bb & 1023;
    int m = bb >> 10;
    const float* src = (m==0)?wq:((m==1)?wk:wv);
    ushort* dst = (m==0)?oq:((m==1)?ok:ov);
    float4 v = ((const float4*)(src + (size_t)row*1024))[t];
    float sc = (t<128)?2.f:1.f;
    float ss = sc*sc*(v.x*v.x + v.y*v.y + v.z*v.z + v.w*v.w);
    #pragma unroll
    for (int off=1; off<64; off<<=1) ss += __shfl_xor(ss, off);
    int w = t>>6, lane = t&63;
    if (lane==0) sp[w]=ss;
    __syncthreads();
    float tot = sp[0]+sp[1]+sp[2]+sp[3];
    float inv = rsqrtf(fmaxf(tot,1e-20f)) * sc;
    union { ushort s[4]; uint2 u; } o;
    o.s[0]=f2bf(v.x*inv); o.s[1]=f2bf(v.y*inv); o.s[2]=f2bf(v.z*inv); o.s[3]=f2bf(v.w*inv);
    ((uint2*)(dst + (size_t)row*1024))[t] = o.u;
  } else if (bid < 5632){
    int i = (bid-5120)*256 + t;
    float sc = ((i>>7) < 512) ? 2.f : 1.f;
    const float4* x4 = (const float4*)wo;
    float4 a = x4[2*i], b = x4[2*i+1];
    union { ushort s[8]; uint4 u; } uu;
    uu.s[0]=f2bf(a.x*sc); uu.s[1]=f2bf(a.y*sc); uu.s[2]=f2bf(a.z*sc); uu.s[3]=f2bf(a.w*sc);
    uu.s[4]=f2bf(b.x*sc); uu.s[5]=f2bf(b.y*sc); uu.s[6]=f2bf(b.z*sc); uu.s[7]=f2bf(b.w*sc);
    ((uint4*)wob)[i] = uu.u;
  } else {
    int rb = bid - 5632;
    float4 a = {0.f,0.f,0.f,0.f};
    #pragma unroll 4
    for (int r=0;r<32;r++){
      int row = rb*32+r;
      float4 v = ((const float4*)wo)[row*256 + t];
      float s2 = (row<512)?4.f:1.f;
      a.x += s2*v.x*v.x; a.y += s2*v.y*v.y; a.z += s2*v.z*v.z; a.w += s2*v.w*v.w;
    }
    ((float4*)part)[rb*256 + t] = a;
  }
}

__global__ __launch_bounds__(256) void wo_csum_kernel(const float* __restrict__ part,
                                                      float* __restrict__ colsum){
  int c = blockIdx.x*256 + threadIdx.x;
  float s = 0.f;
  #pragma unroll
  for (int j=0;j<32;j++) s += part[j*1024 + c];
  colsum[c] = s;
}

// ------------- fused 64x128 B^T GEMM, BK=32, 2-barrier, XOR-chunk-swizzled LDS ----
// r13-proven structure (best measured). Staging: lane = srow*4 + sch (consecutive
// lanes = consecutive 16B chunks -> full coalescing). Source chunk sch^(srow&3)
// permutes within each row's 64B line; fragment read uses l4^(l15&3).
// NZ=3: z=0 q [bh][n][d] head-norm + chan scale(incl log2e); z=1 k head-norm;
//       z=2 v TRANSPOSED [bh][d][n], colsum folded.   NZ=1: fp32 out to dst0.
template<int NZ>
__global__ __launch_bounds__(256, 2) void gemm_fused_kernel(
    const ushort* __restrict__ A,
    const ushort* __restrict__ B0, const ushort* __restrict__ B1, const ushort* __restrict__ B2,
    void* dst0, void* dst1, void* dst2,
    const float* __restrict__ qparam, const float* __restrict__ colsum, int K)
{
  __shared__ ushort As[64*32];          // 4KB
  __shared__ ushort Bs[NZ*128*32];      // 8KB per z
  const int bm = blockIdx.x*64, bn = blockIdx.y*128;
  const int tid = threadIdx.x, lane = tid&63, w = tid>>6;
  const int wr = w>>1, wc = w&1;
  const int l15 = lane&15, l4 = lane>>4;
  const int srow = lane>>2, sch = lane&3;
  const int scol = (sch ^ (srow&3))*8;      // swizzled source chunk (ushorts)

  const f32x4 zero4 = {0.f,0.f,0.f,0.f};
  f32x4 acc[NZ][2][4];
  #pragma unroll
  for (int z=0;z<NZ;z++)
    #pragma unroll
    for (int m=0;m<2;m++)
      #pragma unroll
      for (int n=0;n<4;n++) acc[z][m][n] = zero4;

  for (int k0=0; k0<K; k0+=32){
    __syncthreads();
    GLOAD16(A + (size_t)(bm + w*16 + srow)*K + k0 + scol, &As[w*512]);
    #pragma unroll
    for (int j=0;j<NZ*2;j++){
      int seg = j*4 + w;
      int z = seg>>3, s = seg&7;
      const ushort* Bp = (z==0)?B0:((z==1)?B1:B2);
      GLOAD16(Bp + (size_t)(bn + s*16 + srow)*K + k0 + scol, &Bs[seg*512]);
    }
    __syncthreads();
    bf16x8 af[2];
    #pragma unroll
    for (int m=0;m<2;m++)
      af[m] = *(const bf16x8*)&As[(wr*32 + m*16 + l15)*32 + ((l4 ^ (l15&3))*8)];
    #pragma unroll
    for (int z=0;z<NZ;z++){
      bf16x8 bfr[4];
      #pragma unroll
      for (int n=0;n<4;n++)
        bfr[n] = *(const bf16x8*)&Bs[z*4096 + (wc*64 + n*16 + l15)*32 + ((l4 ^ (l15&3))*8)];
      #pragma unroll
      for (int m=0;m<2;m++)
        #pragma unroll
        for (int n=0;n<4;n++)
          acc[z][m][n] = MFMA_BF16(af[m], bfr[n], acc[z][m][n]);
    }
  }

  if (NZ==3){
    #pragma unroll
    for (int z=0;z<3;z++){
      ushort* dst = (ushort*)((z==0)?dst0:((z==1)?dst1:dst2));
      float qs[4];
      #pragma unroll
      for (int n=0;n<4;n++){
        int e = bn + wc*64 + n*16 + l15;
        if (z==0)      qs[n] = qparam[e]*8192.f*1.44269504088896f;
        else if (z==2) qs[n] = rsqrtf(fmaxf(colsum[e],1e-20f));
        else           qs[n] = 1.f;
      }
      #pragma unroll
      for (int m=0;m<2;m++){
        float ssq[4] = {0.f,0.f,0.f,0.f};
        if (z<2){
          #pragma unroll
          for (int reg=0;reg<4;reg++){
            float s=0.f;
            #pragma unroll
            for (int n=0;n<4;n++){
              float scl2 = (n<2)?4.f:1.f;
              float vv = acc[z][m][n][reg];
              s += scl2*vv*vv;
            }
            ssq[reg]=s;
          }
          #pragma unroll
          for (int d=1; d<16; d<<=1){
            #pragma unroll
            for (int reg=0;reg<4;reg++) ssq[reg] += __shfl_xor(ssq[reg], d);
          }
        }
        #pragma unroll
        for (int n=0;n<4;n++){
          float scl = (n<2)?2.f:1.f;
          #pragma unroll
          for (int reg=0;reg<4;reg++){
            float val = acc[z][m][n][reg];
            if (z<2) val = val*scl*rsqrtf(fmaxf(ssq[reg],1e-20f))*qs[n];
            else     val = val*qs[n];
            int row = bm + wr*32 + m*16 + l4*4 + reg;
            int col = bn + wc*64 + n*16 + l15;
            int b = row>>10, nn = row&1023, h = col>>6, d = col&63;
            if (z==2)
              dst[(((size_t)b*HEADS+h)*DH + d)*SEQ + nn] = f2bf(val);     // V^T
            else
              dst[(((size_t)b*HEADS+h)*SEQ + nn)*DH + d] = f2bf(val);
          }
        }
      }
    }
  } else {
    float* outp = (float*)dst0;
    #pragma unroll
    for (int m=0;m<2;m++)
      #pragma unroll
      for (int n=0;n<4;n++)
        #pragma unroll
        for (int reg=0;reg<4;reg++){
          int row = bm + wr*32 + m*16 + l4*4 + reg;
          int col = bn + wc*64 + n*16 + l15;
          outp[(size_t)row*DIMD + col] = acc[0][m][n][reg];
        }
  }
}

// ------------- attention: 32x32 swapped-QK^T, shfl_xor(32) cross-lane -------------
// + T13 defer-max: skip O/l rescale when tile max within 8 (log2) of running max.
template<int NS, bool MASK>
__device__ __forceinline__ void attn_iter(
    const ushort* __restrict__ Kp, const ushort* __restrict__ Vp,
    int kvb, const bf16x8 (&qf)[4], int l31, int l1,
    f32x16& o0, f32x16& o1, float& m_s, float& l_s)
{
  // ---- loads up front ----
  bf16x8 kfa[4], kfb[4];
  #pragma unroll
  for (int md=0; md<4; md++)
    kfa[md] = *(const bf16x8*)&Kp[(size_t)(kvb + l31)*DH + md*16 + l1*8];
  if (NS==2){
    #pragma unroll
    for (int md=0; md<4; md++)
      kfb[md] = *(const bf16x8*)&Kp[(size_t)(kvb + 32 + l31)*DH + md*16 + l1*8];
  }
  bf16x8 vf0[2*NS], vf1[2*NS];
  #pragma unroll
  for (int kc=0; kc<2*NS; kc++){
    vf0[kc] = *(const bf16x8*)&Vp[(size_t)l31*SEQ      + kvb + kc*16 + l1*8];
    vf1[kc] = *(const bf16x8*)&Vp[(size_t)(32+l31)*SEQ + kvb + kc*16 + l1*8];
  }

  // ---- S^T ----
  f32x16 s0 = ZERO16, s1 = ZERO16;
  __builtin_amdgcn_s_setprio(1);
  #pragma unroll
  for (int md=0; md<4; md++) s0 = MFMA32(kfa[md], qf[md], s0);
  if (NS==2){
    #pragma unroll
    for (int md=0; md<4; md++) s1 = MFMA32(kfb[md], qf[md], s1);
  }
  __builtin_amdgcn_s_setprio(0);

  if (MASK){
    f32x16& sm = (NS==2) ? s1 : s0;
    #pragma unroll
    for (int r=0;r<16;r++){
      int kvl = (r&3) + 8*(r>>2) + 4*l1;
      if (kvl > l31) sm[r] = -3.0e38f;
    }
  }

  // ---- online softmax (log2 domain), lane-local + shfl_xor(32) combine ----
  float mx = -3.0e38f;
  #pragma unroll
  for (int r=0;r<16;r++) mx = fmaxf(mx, s0[r]);
  if (NS==2){
    #pragma unroll
    for (int r=0;r<16;r++) mx = fmaxf(mx, s1[r]);
  }
  mx = fmaxf(mx, __shfl_xor(mx, 32));
  // T13 defer-max: only rescale when max grew by > 8 (log2 units); P <= 2^8 is
  // safe in f32/bf16. Branch is wave-uniform (__all).
  if (!__all(mx - m_s <= 8.0f)){
    float mnew = fmaxf(m_s, mx);
    float alpha = __builtin_amdgcn_exp2f(m_s - mnew);
    l_s *= alpha;
    #pragma unroll
    for (int r=0;r<16;r++){ o0[r] *= alpha; o1[r] *= alpha; }
    m_s = mnew;
  }
  float rs = 0.f;
  #pragma unroll
  for (int r=0;r<16;r++){ s0[r] = __builtin_amdgcn_exp2f(s0[r]-m_s); rs += s0[r]; }
  if (NS==2){
    #pragma unroll
    for (int r=0;r<16;r++){ s1[r] = __builtin_amdgcn_exp2f(s1[r]-m_s); rs += s1[r]; }
  }
  rs += __shfl_xor(rs, 32);
  l_s += rs;

  // ---- P -> bf16 pairs; shfl_xor(32) + select builds B-fragments ----
  uint ru[16];
  #pragma unroll
  for (int j=0;j<8;j++) ru[j] = packbf2(s0[2*j], s0[2*j+1]);
  if (NS==2){
    #pragma unroll
    for (int j=0;j<8;j++) ru[8+j] = packbf2(s1[2*j], s1[2*j+1]);
  }
  union U4 { uint u[4]; bf16x8 v; };
  U4 fr[2*NS];
  #pragma unroll
  for (int j=0;j<NS;j++){
    uint px[8];
    #pragma unroll
    for (int k=0;k<8;k++) px[k] = xswap32(ru[8*j+k]);
    fr[2*j].u[0]   = l1 ? px[2]      : ru[8*j+0];
    fr[2*j].u[1]   = l1 ? px[3]      : ru[8*j+1];
    fr[2*j].u[2]   = l1 ? ru[8*j+2]  : px[0];
    fr[2*j].u[3]   = l1 ? ru[8*j+3]  : px[1];
    fr[2*j+1].u[0] = l1 ? px[6]      : ru[8*j+4];
    fr[2*j+1].u[1] = l1 ? px[7]      : ru[8*j+5];
    fr[2*j+1].u[2] = l1 ? ru[8*j+6]  : px[4];
    fr[2*j+1].u[3] = l1 ? ru[8*j+7]  : px[5];
  }

  // ---- PV: O^T[d][q] += V^T fragments x P ----
  __builtin_amdgcn_s_setprio(1);
  #pragma unroll
  for (int kc=0; kc<2*NS; kc++){
    o0 = MFMA32(vf0[kc], fr[kc].v, o0);
    o1 = MFMA32(vf1[kc], fr[kc].v, o1);
  }
  __builtin_amdgcn_s_setprio(0);
}

__device__ __forceinline__ void process_tile(
    int t, int par, int bh,
    const ushort* __restrict__ Q, const ushort* __restrict__ K,
    const ushort* __restrict__ VT, ushort* __restrict__ O,
    int l31, int l1)
{
  const size_t base  = (size_t)bh * SEQ * DH;
  const size_t vbase = (size_t)bh * DH * SEQ;
  const ushort* Kp = K + base;
  const ushort* Vp = VT + vbase;
  const int qbase = t*64 + par*32;

  bf16x8 qf[4];
  #pragma unroll
  for (int md=0; md<4; md++)
    qf[md] = *(const bf16x8*)&Q[base + (size_t)(qbase + l31)*DH + md*16 + l1*8];

  f32x16 o0 = ZERO16, o1 = ZERO16;
  float m_s = -3.0e38f, l_s = 0.f;

  for (int kt=0; kt<t; kt++)
    attn_iter<2,false>(Kp, Vp, kt*64, qf, l31, l1, o0, o1, m_s, l_s);
  if (par) attn_iter<2,true>(Kp, Vp, t*64, qf, l31, l1, o0, o1, m_s, l_s);
  else     attn_iter<1,true>(Kp, Vp, t*64, qf, l31, l1, o0, o1, m_s, l_s);

  float li = 1.0f / l_s;
  int b = bh >> 4, hh = bh & 15;
  int n = qbase + l31;
  ushort* orow = O + ((size_t)b*SEQ + n)*DIMD + hh*64;
  #pragma unroll
  for (int r=0;r<16;r++){
    int dl = (r&3) + 8*(r>>2) + 4*l1;
    orow[dl]    = f2bf(o0[r]*li);
    orow[32+dl] = f2bf(o1[r]*li);
  }
}

__global__ __launch_bounds__(256, 2) void attn_kernel(
    const ushort* __restrict__ Q, const ushort* __restrict__ K, const ushort* __restrict__ VT,
    ushort* __restrict__ O)
{
  int id = blockIdx.x;                  // 512 blocks
  int p  = id >> 6;                     // pair index 0..7 -> tiles {p, 15-p}
  int r  = id & 63;
  int bh = (r&7)*8 + (r>>3);            // XCD x serves bh in [8x, 8x+8)
  int tid = threadIdx.x, wi = tid>>6, lane = tid&63;
  int l31 = lane & 31, l1 = lane >> 5;
  int sel = (wi & 1) ^ (bh & 1);        // balance SIMD load across co-resident blocks
  int t   = sel ? (15-p) : p;
  int par = wi >> 1;
  process_tile(t, par, bh, Q, K, VT, O, l31, l1);
}

extern "C" void kernel_launch(void* const* d_in, const int* in_sizes, int n_in,
                              void* d_out, int out_size, void* d_ws, size_t ws_size,
                              hipStream_t stream)
{
  const float* x      = (const float*)d_in[0];
  const float* w_q    = (const float*)d_in[1];
  const float* w_k    = (const float*)d_in[2];
  const float* w_v    = (const float*)d_in[3];
  const float* w_o    = (const float*)d_in[4];
  const float* qparam = (const float*)d_in[5];
  char* ws = (char*)d_ws;
  const size_t MB = 1u<<20;
  ushort* xb  = (ushort*)(ws);             // 8MB; reused as attention output
  ushort* wqb = (ushort*)(ws + 8*MB);      // 2MB each
  ushort* wkb = (ushort*)(ws + 10*MB);
  ushort* wvb = (ushort*)(ws + 12*MB);
  ushort* wob = (ushort*)(ws + 14*MB);
  ushort* qd  = (ushort*)(ws + 16*MB);     // 8MB each
  ushort* kd  = (ushort*)(ws + 24*MB);
  ushort* vd  = (ushort*)(ws + 32*MB);     // V^T [bh][d][n], wo-colsum folded
  ushort* att = xb;
  float* part = (float*)(ws + 40*MB);      // 128KB scratch
  float* colsum = (float*)d_out + (out_size - 1024);  // overwritten by final GEMM

  prep_kernel<<<dim3(5664), dim3(256), 0, stream>>>(
      x, w_q, w_k, w_v, w_o, xb, wqb, wkb, wvb, wob, part);
  wo_csum_kernel<<<dim3(4), dim3(256), 0, stream>>>(part, colsum);
  gemm_fused_kernel<3><<<dim3(64,8), dim3(256), 0, stream>>>(
      xb, wqb, wkb, wvb, (void*)qd, (void*)kd, (void*)vd, qparam, colsum, DIMD);
  attn_kernel<<<dim3(512), dim3(256), 0, stream>>>(qd, kd, vd, att);
  gemm_fused_kernel<1><<<dim3(64,8), dim3(256), 0, stream>>>(
      att, wob, wob, wob, d_out, nullptr, nullptr, nullptr, nullptr, DIMD);
}

// Round 17
// 116.860 us; speedup vs baseline: 2.0351x; 1.0292x over previous
//
#include <hip/hip_runtime.h>
#include <hip/hip_bf16.h>

#define HEADS 16
#define DH    64
#define BATCH 4
#define SEQ   1024
#define DIMD  1024
#define TOK   4096

typedef __attribute__((ext_vector_type(8))) short bf16x8;
typedef __attribute__((ext_vector_type(4))) float f32x4;
typedef __attribute__((ext_vector_type(16))) float f32x16;

typedef const void __attribute__((address_space(1)))* gas1_t;
typedef void __attribute__((address_space(3)))* las3_t;

#define GLOAD16(g,l) __builtin_amdgcn_global_load_lds((gas1_t)(g),(las3_t)(l),16,0,0)
#define MFMA_BF16(a,b,c) __builtin_amdgcn_mfma_f32_16x16x32_bf16((a),(b),(c),0,0,0)
#define MFMA32(a,b,c) __builtin_amdgcn_mfma_f32_32x32x16_bf16((a),(b),(c),0,0,0)
#define ZERO16 {0.f,0.f,0.f,0.f,0.f,0.f,0.f,0.f,0.f,0.f,0.f,0.f,0.f,0.f,0.f,0.f}

__device__ __forceinline__ ushort f2bf(float f){
  __hip_bfloat16 h = __float2bfloat16(f);
  return *reinterpret_cast<ushort*>(&h);
}
__device__ __forceinline__ uint packbf2(float a, float b){
  return (uint)f2bf(a) | ((uint)f2bf(b) << 16);
}
__device__ __forceinline__ uint xswap32(uint x){   // lane l <-> lane l^32
  return (uint)__shfl_xor((int)x, 32);
}

// ------------- merged prep: cast_x | norm_rows(wq,wk,wv) | cast_wo | wo_part -------------
__global__ __launch_bounds__(256) void prep_kernel(
    const float* __restrict__ x,
    const float* __restrict__ wq, const float* __restrict__ wk, const float* __restrict__ wv,
    const float* __restrict__ wo,
    ushort* __restrict__ xb,
    ushort* __restrict__ oq, ushort* __restrict__ ok, ushort* __restrict__ ov,
    ushort* __restrict__ wob, float* __restrict__ part)
{
  __shared__ float sp[4];
  int bid = blockIdx.x, t = threadIdx.x;
  if (bid < 2048){
    int i = bid*256 + t;
    const float4* x4 = (const float4*)x;
    float4 a = x4[2*i], b = x4[2*i+1];
    union { ushort s[8]; uint4 u; } uu;
    uu.s[0]=f2bf(a.x); uu.s[1]=f2bf(a.y); uu.s[2]=f2bf(a.z); uu.s[3]=f2bf(a.w);
    uu.s[4]=f2bf(b.x); uu.s[5]=f2bf(b.y); uu.s[6]=f2bf(b.z); uu.s[7]=f2bf(b.w);
    ((uint4*)xb)[i] = uu.u;
  } else if (bid < 5120){
    int bb = bid - 2048;
    int row = bb & 1023;
    int m = bb >> 10;
    const float* src = (m==0)?wq:((m==1)?wk:wv);
    ushort* dst = (m==0)?oq:((m==1)?ok:ov);
    float4 v = ((const float4*)(src + (size_t)row*1024))[t];
    float sc = (t<128)?2.f:1.f;
    float ss = sc*sc*(v.x*v.x + v.y*v.y + v.z*v.z + v.w*v.w);
    #pragma unroll
    for (int off=1; off<64; off<<=1) ss += __shfl_xor(ss, off);
    int w = t>>6, lane = t&63;
    if (lane==0) sp[w]=ss;
    __syncthreads();
    float tot = sp[0]+sp[1]+sp[2]+sp[3];
    float inv = rsqrtf(fmaxf(tot,1e-20f)) * sc;
    union { ushort s[4]; uint2 u; } o;
    o.s[0]=f2bf(v.x*inv); o.s[1]=f2bf(v.y*inv); o.s[2]=f2bf(v.z*inv); o.s[3]=f2bf(v.w*inv);
    ((uint2*)(dst + (size_t)row*1024))[t] = o.u;
  } else if (bid < 5632){
    int i = (bid-5120)*256 + t;
    float sc = ((i>>7) < 512) ? 2.f : 1.f;
    const float4* x4 = (const float4*)wo;
    float4 a = x4[2*i], b = x4[2*i+1];
    union { ushort s[8]; uint4 u; } uu;
    uu.s[0]=f2bf(a.x*sc); uu.s[1]=f2bf(a.y*sc); uu.s[2]=f2bf(a.z*sc); uu.s[3]=f2bf(a.w*sc);
    uu.s[4]=f2bf(b.x*sc); uu.s[5]=f2bf(b.y*sc); uu.s[6]=f2bf(b.z*sc); uu.s[7]=f2bf(b.w*sc);
    ((uint4*)wob)[i] = uu.u;
  } else {
    int rb = bid - 5632;
    float4 a = {0.f,0.f,0.f,0.f};
    #pragma unroll 4
    for (int r=0;r<32;r++){
      int row = rb*32+r;
      float4 v = ((const float4*)wo)[row*256 + t];
      float s2 = (row<512)?4.f:1.f;
      a.x += s2*v.x*v.x; a.y += s2*v.y*v.y; a.z += s2*v.z*v.z; a.w += s2*v.w*v.w;
    }
    ((float4*)part)[rb*256 + t] = a;
  }
}

__global__ __launch_bounds__(256) void wo_csum_kernel(const float* __restrict__ part,
                                                      float* __restrict__ colsum){
  int c = blockIdx.x*256 + threadIdx.x;
  float s = 0.f;
  #pragma unroll
  for (int j=0;j<32;j++) s += part[j*1024 + c];
  colsum[c] = s;
}

// ------------- fused 64x64 B^T GEMM, BK=32, 2-barrier, XOR-chunk-swizzled LDS ----
// Same per-step structure as the proven r13 kernel; tile shrunk 64x128 -> 64x64
// so grid doubles (1024 blocks = 4 blocks/CU = 16 waves/CU). Blocks don't share
// barriers -> co-resident blocks' MFMA fills each other's stage/barrier stalls.
// Each wave owns 16 rows x 64 cols (one full head span): head-norm reduce is
// wave-local, identical to before.
// NZ=3: z=0 q [bh][n][d] head-norm + chan scale(incl log2e); z=1 k head-norm;
//       z=2 v TRANSPOSED [bh][d][n], colsum folded.   NZ=1: fp32 out to dst0.
template<int NZ>
__global__ __launch_bounds__(256, 4) void gemm_fused_kernel(
    const ushort* __restrict__ A,
    const ushort* __restrict__ B0, const ushort* __restrict__ B1, const ushort* __restrict__ B2,
    void* dst0, void* dst1, void* dst2,
    const float* __restrict__ qparam, const float* __restrict__ colsum, int K)
{
  __shared__ ushort As[64*32];          // 4KB
  __shared__ ushort Bs[NZ*64*32];       // 4KB per z
  const int bm = blockIdx.x*64, bn = blockIdx.y*64;
  const int tid = threadIdx.x, lane = tid&63, w = tid>>6;
  const int l15 = lane&15, l4 = lane>>4;
  const int srow = lane>>2, sch = lane&3;
  const int scol = (sch ^ (srow&3))*8;      // swizzled source chunk (ushorts)

  const f32x4 zero4 = {0.f,0.f,0.f,0.f};
  f32x4 acc[NZ][4];
  #pragma unroll
  for (int z=0;z<NZ;z++)
    #pragma unroll
    for (int n=0;n<4;n++) acc[z][n] = zero4;

  for (int k0=0; k0<K; k0+=32){
    __syncthreads();
    // wave w stages rows [w*16, w*16+16) of A and of each B_z
    GLOAD16(A + (size_t)(bm + w*16 + srow)*K + k0 + scol, &As[w*512]);
    #pragma unroll
    for (int j=0;j<NZ;j++){
      const ushort* Bp = (j==0)?B0:((j==1)?B1:B2);
      GLOAD16(Bp + (size_t)(bn + w*16 + srow)*K + k0 + scol, &Bs[j*2048 + w*512]);
    }
    __syncthreads();
    bf16x8 af = *(const bf16x8*)&As[(w*16 + l15)*32 + ((l4 ^ (l15&3))*8)];
    #pragma unroll
    for (int z=0;z<NZ;z++){
      bf16x8 bfr[4];
      #pragma unroll
      for (int n=0;n<4;n++)
        bfr[n] = *(const bf16x8*)&Bs[z*2048 + (n*16 + l15)*32 + ((l4 ^ (l15&3))*8)];
      #pragma unroll
      for (int n=0;n<4;n++)
        acc[z][n] = MFMA_BF16(af, bfr[n], acc[z][n]);
    }
  }

  if (NZ==3){
    #pragma unroll
    for (int z=0;z<3;z++){
      ushort* dst = (ushort*)((z==0)?dst0:((z==1)?dst1:dst2));
      float qs[4];
      #pragma unroll
      for (int n=0;n<4;n++){
        int e = bn + n*16 + l15;
        if (z==0)      qs[n] = qparam[e]*8192.f*1.44269504088896f;
        else if (z==2) qs[n] = rsqrtf(fmaxf(colsum[e],1e-20f));
        else           qs[n] = 1.f;
      }
      float ssq[4] = {0.f,0.f,0.f,0.f};
      if (z<2){
        #pragma unroll
        for (int reg=0;reg<4;reg++){
          float s=0.f;
          #pragma unroll
          for (int n=0;n<4;n++){
            float scl2 = (n<2)?4.f:1.f;     // d = n*16+l15 < 32 iff n<2
            float vv = acc[z][n][reg];
            s += scl2*vv*vv;
          }
          ssq[reg]=s;
        }
        #pragma unroll
        for (int d=1; d<16; d<<=1){
          #pragma unroll
          for (int reg=0;reg<4;reg++) ssq[reg] += __shfl_xor(ssq[reg], d);
        }
      }
      #pragma unroll
      for (int n=0;n<4;n++){
        float scl = (n<2)?2.f:1.f;
        #pragma unroll
        for (int reg=0;reg<4;reg++){
          float val = acc[z][n][reg];
          if (z<2) val = val*scl*rsqrtf(fmaxf(ssq[reg],1e-20f))*qs[n];
          else     val = val*qs[n];
          int row = bm + w*16 + l4*4 + reg;
          int col = bn + n*16 + l15;
          int b = row>>10, nn = row&1023, h = col>>6, d = col&63;
          if (z==2)
            dst[(((size_t)b*HEADS+h)*DH + d)*SEQ + nn] = f2bf(val);     // V^T
          else
            dst[(((size_t)b*HEADS+h)*SEQ + nn)*DH + d] = f2bf(val);
        }
      }
    }
  } else {
    float* outp = (float*)dst0;
    #pragma unroll
    for (int n=0;n<4;n++)
      #pragma unroll
      for (int reg=0;reg<4;reg++){
        int row = bm + w*16 + l4*4 + reg;
        int col = bn + n*16 + l15;
        outp[(size_t)row*DIMD + col] = acc[0][n][reg];
      }
  }
}

// ------------- attention: 32x32 swapped-QK^T, shfl_xor(32) cross-lane -------------
// + T13 defer-max: skip O/l rescale when tile max within 8 (log2) of running max.
template<int NS, bool MASK>
__device__ __forceinline__ void attn_iter(
    const ushort* __restrict__ Kp, const ushort* __restrict__ Vp,
    int kvb, const bf16x8 (&qf)[4], int l31, int l1,
    f32x16& o0, f32x16& o1, float& m_s, float& l_s)
{
  // ---- loads up front ----
  bf16x8 kfa[4], kfb[4];
  #pragma unroll
  for (int md=0; md<4; md++)
    kfa[md] = *(const bf16x8*)&Kp[(size_t)(kvb + l31)*DH + md*16 + l1*8];
  if (NS==2){
    #pragma unroll
    for (int md=0; md<4; md++)
      kfb[md] = *(const bf16x8*)&Kp[(size_t)(kvb + 32 + l31)*DH + md*16 + l1*8];
  }
  bf16x8 vf0[2*NS], vf1[2*NS];
  #pragma unroll
  for (int kc=0; kc<2*NS; kc++){
    vf0[kc] = *(const bf16x8*)&Vp[(size_t)l31*SEQ      + kvb + kc*16 + l1*8];
    vf1[kc] = *(const bf16x8*)&Vp[(size_t)(32+l31)*SEQ + kvb + kc*16 + l1*8];
  }

  // ---- S^T ----
  f32x16 s0 = ZERO16, s1 = ZERO16;
  __builtin_amdgcn_s_setprio(1);
  #pragma unroll
  for (int md=0; md<4; md++) s0 = MFMA32(kfa[md], qf[md], s0);
  if (NS==2){
    #pragma unroll
    for (int md=0; md<4; md++) s1 = MFMA32(kfb[md], qf[md], s1);
  }
  __builtin_amdgcn_s_setprio(0);

  if (MASK){
    f32x16& sm = (NS==2) ? s1 : s0;
    #pragma unroll
    for (int r=0;r<16;r++){
      int kvl = (r&3) + 8*(r>>2) + 4*l1;
      if (kvl > l31) sm[r] = -3.0e38f;
    }
  }

  // ---- online softmax (log2 domain), lane-local + shfl_xor(32) combine ----
  float mx = -3.0e38f;
  #pragma unroll
  for (int r=0;r<16;r++) mx = fmaxf(mx, s0[r]);
  if (NS==2){
    #pragma unroll
    for (int r=0;r<16;r++) mx = fmaxf(mx, s1[r]);
  }
  mx = fmaxf(mx, __shfl_xor(mx, 32));
  if (!__all(mx - m_s <= 8.0f)){
    float mnew = fmaxf(m_s, mx);
    float alpha = __builtin_amdgcn_exp2f(m_s - mnew);
    l_s *= alpha;
    #pragma unroll
    for (int r=0;r<16;r++){ o0[r] *= alpha; o1[r] *= alpha; }
    m_s = mnew;
  }
  float rs = 0.f;
  #pragma unroll
  for (int r=0;r<16;r++){ s0[r] = __builtin_amdgcn_exp2f(s0[r]-m_s); rs += s0[r]; }
  if (NS==2){
    #pragma unroll
    for (int r=0;r<16;r++){ s1[r] = __builtin_amdgcn_exp2f(s1[r]-m_s); rs += s1[r]; }
  }
  rs += __shfl_xor(rs, 32);
  l_s += rs;

  // ---- P -> bf16 pairs; shfl_xor(32) + select builds B-fragments ----
  uint ru[16];
  #pragma unroll
  for (int j=0;j<8;j++) ru[j] = packbf2(s0[2*j], s0[2*j+1]);
  if (NS==2){
    #pragma unroll
    for (int j=0;j<8;j++) ru[8+j] = packbf2(s1[2*j], s1[2*j+1]);
  }
  union U4 { uint u[4]; bf16x8 v; };
  U4 fr[2*NS];
  #pragma unroll
  for (int j=0;j<NS;j++){
    uint px[8];
    #pragma unroll
    for (int k=0;k<8;k++) px[k] = xswap32(ru[8*j+k]);
    fr[2*j].u[0]   = l1 ? px[2]      : ru[8*j+0];
    fr[2*j].u[1]   = l1 ? px[3]      : ru[8*j+1];
    fr[2*j].u[2]   = l1 ? ru[8*j+2]  : px[0];
    fr[2*j].u[3]   = l1 ? ru[8*j+3]  : px[1];
    fr[2*j+1].u[0] = l1 ? px[6]      : ru[8*j+4];
    fr[2*j+1].u[1] = l1 ? px[7]      : ru[8*j+5];
    fr[2*j+1].u[2] = l1 ? ru[8*j+6]  : px[4];
    fr[2*j+1].u[3] = l1 ? ru[8*j+7]  : px[5];
  }

  // ---- PV: O^T[d][q] += V^T fragments x P ----
  __builtin_amdgcn_s_setprio(1);
  #pragma unroll
  for (int kc=0; kc<2*NS; kc++){
    o0 = MFMA32(vf0[kc], fr[kc].v, o0);
    o1 = MFMA32(vf1[kc], fr[kc].v, o1);
  }
  __builtin_amdgcn_s_setprio(0);
}

__device__ __forceinline__ void process_tile(
    int t, int par, int bh,
    const ushort* __restrict__ Q, const ushort* __restrict__ K,
    const ushort* __restrict__ VT, ushort* __restrict__ O,
    int l31, int l1)
{
  const size_t base  = (size_t)bh * SEQ * DH;
  const size_t vbase = (size_t)bh * DH * SEQ;
  const ushort* Kp = K + base;
  const ushort* Vp = VT + vbase;
  const int qbase = t*64 + par*32;

  bf16x8 qf[4];
  #pragma unroll
  for (int md=0; md<4; md++)
    qf[md] = *(const bf16x8*)&Q[base + (size_t)(qbase + l31)*DH + md*16 + l1*8];

  f32x16 o0 = ZERO16, o1 = ZERO16;
  float m_s = -3.0e38f, l_s = 0.f;

  for (int kt=0; kt<t; kt++)
    attn_iter<2,false>(Kp, Vp, kt*64, qf, l31, l1, o0, o1, m_s, l_s);
  if (par) attn_iter<2,true>(Kp, Vp, t*64, qf, l31, l1, o0, o1, m_s, l_s);
  else     attn_iter<1,true>(Kp, Vp, t*64, qf, l31, l1, o0, o1, m_s, l_s);

  float li = 1.0f / l_s;
  int b = bh >> 4, hh = bh & 15;
  int n = qbase + l31;
  ushort* orow = O + ((size_t)b*SEQ + n)*DIMD + hh*64;
  #pragma unroll
  for (int r=0;r<16;r++){
    int dl = (r&3) + 8*(r>>2) + 4*l1;
    orow[dl]    = f2bf(o0[r]*li);
    orow[32+dl] = f2bf(o1[r]*li);
  }
}

__global__ __launch_bounds__(256, 2) void attn_kernel(
    const ushort* __restrict__ Q, const ushort* __restrict__ K, const ushort* __restrict__ VT,
    ushort* __restrict__ O)
{
  int id = blockIdx.x;                  // 512 blocks
  int p  = id >> 6;                     // pair index 0..7 -> tiles {p, 15-p}
  int r  = id & 63;
  int bh = (r&7)*8 + (r>>3);            // XCD x serves bh in [8x, 8x+8)
  int tid = threadIdx.x, wi = tid>>6, lane = tid&63;
  int l31 = lane & 31, l1 = lane >> 5;
  int sel = (wi & 1) ^ (bh & 1);        // balance SIMD load across co-resident blocks
  int t   = sel ? (15-p) : p;
  int par = wi >> 1;
  process_tile(t, par, bh, Q, K, VT, O, l31, l1);
}

extern "C" void kernel_launch(void* const* d_in, const int* in_sizes, int n_in,
                              void* d_out, int out_size, void* d_ws, size_t ws_size,
                              hipStream_t stream)
{
  const float* x      = (const float*)d_in[0];
  const float* w_q    = (const float*)d_in[1];
  const float* w_k    = (const float*)d_in[2];
  const float* w_v    = (const float*)d_in[3];
  const float* w_o    = (const float*)d_in[4];
  const float* qparam = (const float*)d_in[5];
  char* ws = (char*)d_ws;
  const size_t MB = 1u<<20;
  ushort* xb  = (ushort*)(ws);             // 8MB; reused as attention output
  ushort* wqb = (ushort*)(ws + 8*MB);      // 2MB each
  ushort* wkb = (ushort*)(ws + 10*MB);
  ushort* wvb = (ushort*)(ws + 12*MB);
  ushort* wob = (ushort*)(ws + 14*MB);
  ushort* qd  = (ushort*)(ws + 16*MB);     // 8MB each
  ushort* kd  = (ushort*)(ws + 24*MB);
  ushort* vd  = (ushort*)(ws + 32*MB);     // V^T [bh][d][n], wo-colsum folded
  ushort* att = xb;
  float* part = (float*)(ws + 40*MB);      // 128KB scratch
  float* colsum = (float*)d_out + (out_size - 1024);  // overwritten by final GEMM

  prep_kernel<<<dim3(5664), dim3(256), 0, stream>>>(
      x, w_q, w_k, w_v, w_o, xb, wqb, wkb, wvb, wob, part);
  wo_csum_kernel<<<dim3(4), dim3(256), 0, stream>>>(part, colsum);
  gemm_fused_kernel<3><<<dim3(64,16), dim3(256), 0, stream>>>(
      xb, wqb, wkb, wvb, (void*)qd, (void*)kd, (void*)vd, qparam, colsum, DIMD);
  attn_kernel<<<dim3(512), dim3(256), 0, stream>>>(qd, kd, vd, att);
  gemm_fused_kernel<1><<<dim3(64,16), dim3(256), 0, stream>>>(
      att, wob, wob, wob, d_out, nullptr, nullptr, nullptr, nullptr, DIMD);
}

// Round 18
// 116.440 us; speedup vs baseline: 2.0425x; 1.0036x over previous
//
#include <hip/hip_runtime.h>
#include <hip/hip_bf16.h>

#define HEADS 16
#define DH    64
#define BATCH 4
#define SEQ   1024
#define DIMD  1024
#define TOK   4096

typedef __attribute__((ext_vector_type(8))) short bf16x8;
typedef __attribute__((ext_vector_type(4))) float f32x4;
typedef __attribute__((ext_vector_type(16))) float f32x16;

typedef const void __attribute__((address_space(1)))* gas1_t;
typedef void __attribute__((address_space(3)))* las3_t;

#define GLOAD16(g,l) __builtin_amdgcn_global_load_lds((gas1_t)(g),(las3_t)(l),16,0,0)
#define MFMA_BF16(a,b,c) __builtin_amdgcn_mfma_f32_16x16x32_bf16((a),(b),(c),0,0,0)
#define MFMA32(a,b,c) __builtin_amdgcn_mfma_f32_32x32x16_bf16((a),(b),(c),0,0,0)
#define ZERO16 {0.f,0.f,0.f,0.f,0.f,0.f,0.f,0.f,0.f,0.f,0.f,0.f,0.f,0.f,0.f,0.f}

__device__ __forceinline__ ushort f2bf(float f){
  __hip_bfloat16 h = __float2bfloat16(f);
  return *reinterpret_cast<ushort*>(&h);
}
__device__ __forceinline__ uint packbf2(float a, float b){
  return (uint)f2bf(a) | ((uint)f2bf(b) << 16);
}
__device__ __forceinline__ uint xswap32(uint x){   // lane l <-> lane l^32
  return (uint)__shfl_xor((int)x, 32);
}

// ------------- merged prep: cast_x | norm_rows(wq,wk,wv) | cast_wo | wo_part -------------
__global__ __launch_bounds__(256) void prep_kernel(
    const float* __restrict__ x,
    const float* __restrict__ wq, const float* __restrict__ wk, const float* __restrict__ wv,
    const float* __restrict__ wo,
    ushort* __restrict__ xb,
    ushort* __restrict__ oq, ushort* __restrict__ ok, ushort* __restrict__ ov,
    ushort* __restrict__ wob, float* __restrict__ part)
{
  __shared__ float sp[4];
  int bid = blockIdx.x, t = threadIdx.x;
  if (bid < 2048){
    int i = bid*256 + t;
    const float4* x4 = (const float4*)x;
    float4 a = x4[2*i], b = x4[2*i+1];
    union { ushort s[8]; uint4 u; } uu;
    uu.s[0]=f2bf(a.x); uu.s[1]=f2bf(a.y); uu.s[2]=f2bf(a.z); uu.s[3]=f2bf(a.w);
    uu.s[4]=f2bf(b.x); uu.s[5]=f2bf(b.y); uu.s[6]=f2bf(b.z); uu.s[7]=f2bf(b.w);
    ((uint4*)xb)[i] = uu.u;
  } else if (bid < 5120){
    int bb = bid - 2048;
    int row = bb & 1023;
    int m = bb >> 10;
    const float* src = (m==0)?wq:((m==1)?wk:wv);
    ushort* dst = (m==0)?oq:((m==1)?ok:ov);
    float4 v = ((const float4*)(src + (size_t)row*1024))[t];
    float sc = (t<128)?2.f:1.f;
    float ss = sc*sc*(v.x*v.x + v.y*v.y + v.z*v.z + v.w*v.w);
    #pragma unroll
    for (int off=1; off<64; off<<=1) ss += __shfl_xor(ss, off);
    int w = t>>6, lane = t&63;
    if (lane==0) sp[w]=ss;
    __syncthreads();
    float tot = sp[0]+sp[1]+sp[2]+sp[3];
    float inv = rsqrtf(fmaxf(tot,1e-20f)) * sc;
    union { ushort s[4]; uint2 u; } o;
    o.s[0]=f2bf(v.x*inv); o.s[1]=f2bf(v.y*inv); o.s[2]=f2bf(v.z*inv); o.s[3]=f2bf(v.w*inv);
    ((uint2*)(dst + (size_t)row*1024))[t] = o.u;
  } else if (bid < 5632){
    int i = (bid-5120)*256 + t;
    float sc = ((i>>7) < 512) ? 2.f : 1.f;
    const float4* x4 = (const float4*)wo;
    float4 a = x4[2*i], b = x4[2*i+1];
    union { ushort s[8]; uint4 u; } uu;
    uu.s[0]=f2bf(a.x*sc); uu.s[1]=f2bf(a.y*sc); uu.s[2]=f2bf(a.z*sc); uu.s[3]=f2bf(a.w*sc);
    uu.s[4]=f2bf(b.x*sc); uu.s[5]=f2bf(b.y*sc); uu.s[6]=f2bf(b.z*sc); uu.s[7]=f2bf(b.w*sc);
    ((uint4*)wob)[i] = uu.u;
  } else {
    int rb = bid - 5632;
    float4 a = {0.f,0.f,0.f,0.f};
    #pragma unroll 4
    for (int r=0;r<32;r++){
      int row = rb*32+r;
      float4 v = ((const float4*)wo)[row*256 + t];
      float s2 = (row<512)?4.f:1.f;
      a.x += s2*v.x*v.x; a.y += s2*v.y*v.y; a.z += s2*v.z*v.z; a.w += s2*v.w*v.w;
    }
    ((float4*)part)[rb*256 + t] = a;
  }
}

__global__ __launch_bounds__(256) void wo_csum_kernel(const float* __restrict__ part,
                                                      float* __restrict__ colsum){
  int c = blockIdx.x*256 + threadIdx.x;
  float s = 0.f;
  #pragma unroll
  for (int j=0;j<32;j++) s += part[j*1024 + c];
  colsum[c] = s;
}

// ------------- fused 64x64 B^T GEMM, 2-step-unrolled staging (one barrier pair
// per 64-K), XOR-chunk-swizzled LDS. Same proven order: barrier -> stage both
// sub-buffers -> barrier -> compute both. 4 blocks/CU preserved (LDS<=32KB).
// NZ=3: z=0 q [bh][n][d] head-norm + chan scale(incl log2e); z=1 k head-norm;
//       z=2 v TRANSPOSED [bh][d][n], colsum folded.   NZ=1: fp32 out to dst0.
template<int NZ>
__global__ __launch_bounds__(256, 4) void gemm_fused_kernel(
    const ushort* __restrict__ A,
    const ushort* __restrict__ B0, const ushort* __restrict__ B1, const ushort* __restrict__ B2,
    void* dst0, void* dst1, void* dst2,
    const float* __restrict__ qparam, const float* __restrict__ colsum, int K)
{
  __shared__ ushort As[2][64*32];         // 2 x 4KB
  __shared__ ushort Bs[2][NZ*64*32];      // 2 x NZ x 4KB
  const int bm = blockIdx.x*64, bn = blockIdx.y*64;
  const int tid = threadIdx.x, lane = tid&63, w = tid>>6;
  const int l15 = lane&15, l4 = lane>>4;
  const int srow = lane>>2, sch = lane&3;
  const int scol = (sch ^ (srow&3))*8;      // swizzled source chunk (ushorts)

  const f32x4 zero4 = {0.f,0.f,0.f,0.f};
  f32x4 acc[NZ][4];
  #pragma unroll
  for (int z=0;z<NZ;z++)
    #pragma unroll
    for (int n=0;n<4;n++) acc[z][n] = zero4;

  for (int k0=0; k0<K; k0+=64){
    __syncthreads();
    // stage BOTH 32-wide sub-tiles (same wave, same order as proven structure)
    #pragma unroll
    for (int h=0;h<2;h++){
      GLOAD16(A + (size_t)(bm + w*16 + srow)*K + k0 + h*32 + scol, &As[h][w*512]);
      #pragma unroll
      for (int j=0;j<NZ;j++){
        const ushort* Bp = (j==0)?B0:((j==1)?B1:B2);
        GLOAD16(Bp + (size_t)(bn + w*16 + srow)*K + k0 + h*32 + scol,
                &Bs[h][j*2048 + w*512]);
      }
    }
    __syncthreads();
    #pragma unroll
    for (int h=0;h<2;h++){
      bf16x8 af = *(const bf16x8*)&As[h][(w*16 + l15)*32 + ((l4 ^ (l15&3))*8)];
      #pragma unroll
      for (int z=0;z<NZ;z++){
        bf16x8 bfr[4];
        #pragma unroll
        for (int n=0;n<4;n++)
          bfr[n] = *(const bf16x8*)&Bs[h][z*2048 + (n*16 + l15)*32 + ((l4 ^ (l15&3))*8)];
        #pragma unroll
        for (int n=0;n<4;n++)
          acc[z][n] = MFMA_BF16(af, bfr[n], acc[z][n]);
      }
    }
  }

  if (NZ==3){
    #pragma unroll
    for (int z=0;z<3;z++){
      ushort* dst = (ushort*)((z==0)?dst0:((z==1)?dst1:dst2));
      float qs[4];
      #pragma unroll
      for (int n=0;n<4;n++){
        int e = bn + n*16 + l15;
        if (z==0)      qs[n] = qparam[e]*8192.f*1.44269504088896f;
        else if (z==2) qs[n] = rsqrtf(fmaxf(colsum[e],1e-20f));
        else           qs[n] = 1.f;
      }
      float ssq[4] = {0.f,0.f,0.f,0.f};
      if (z<2){
        #pragma unroll
        for (int reg=0;reg<4;reg++){
          float s=0.f;
          #pragma unroll
          for (int n=0;n<4;n++){
            float scl2 = (n<2)?4.f:1.f;
            float vv = acc[z][n][reg];
            s += scl2*vv*vv;
          }
          ssq[reg]=s;
        }
        #pragma unroll
        for (int d=1; d<16; d<<=1){
          #pragma unroll
          for (int reg=0;reg<4;reg++) ssq[reg] += __shfl_xor(ssq[reg], d);
        }
      }
      #pragma unroll
      for (int n=0;n<4;n++){
        float scl = (n<2)?2.f:1.f;
        #pragma unroll
        for (int reg=0;reg<4;reg++){
          float val = acc[z][n][reg];
          if (z<2) val = val*scl*rsqrtf(fmaxf(ssq[reg],1e-20f))*qs[n];
          else     val = val*qs[n];
          int row = bm + w*16 + l4*4 + reg;
          int col = bn + n*16 + l15;
          int b = row>>10, nn = row&1023, h = col>>6, d = col&63;
          if (z==2)
            dst[(((size_t)b*HEADS+h)*DH + d)*SEQ + nn] = f2bf(val);     // V^T
          else
            dst[(((size_t)b*HEADS+h)*SEQ + nn)*DH + d] = f2bf(val);
        }
      }
    }
  } else {
    float* outp = (float*)dst0;
    #pragma unroll
    for (int n=0;n<4;n++)
      #pragma unroll
      for (int reg=0;reg<4;reg++){
        int row = bm + w*16 + l4*4 + reg;
        int col = bn + n*16 + l15;
        outp[(size_t)row*DIMD + col] = acc[0][n][reg];
      }
  }
}

// ------------- attention: 32x32 swapped-QK^T, shfl_xor(32) cross-lane -------------
// + T13 defer-max: skip O/l rescale when tile max within 8 (log2) of running max.
template<int NS, bool MASK>
__device__ __forceinline__ void attn_iter(
    const ushort* __restrict__ Kp, const ushort* __restrict__ Vp,
    int kvb, const bf16x8 (&qf)[4], int l31, int l1,
    f32x16& o0, f32x16& o1, float& m_s, float& l_s)
{
  // ---- loads up front ----
  bf16x8 kfa[4], kfb[4];
  #pragma unroll
  for (int md=0; md<4; md++)
    kfa[md] = *(const bf16x8*)&Kp[(size_t)(kvb + l31)*DH + md*16 + l1*8];
  if (NS==2){
    #pragma unroll
    for (int md=0; md<4; md++)
      kfb[md] = *(const bf16x8*)&Kp[(size_t)(kvb + 32 + l31)*DH + md*16 + l1*8];
  }
  bf16x8 vf0[2*NS], vf1[2*NS];
  #pragma unroll
  for (int kc=0; kc<2*NS; kc++){
    vf0[kc] = *(const bf16x8*)&Vp[(size_t)l31*SEQ      + kvb + kc*16 + l1*8];
    vf1[kc] = *(const bf16x8*)&Vp[(size_t)(32+l31)*SEQ + kvb + kc*16 + l1*8];
  }

  // ---- S^T ----
  f32x16 s0 = ZERO16, s1 = ZERO16;
  __builtin_amdgcn_s_setprio(1);
  #pragma unroll
  for (int md=0; md<4; md++) s0 = MFMA32(kfa[md], qf[md], s0);
  if (NS==2){
    #pragma unroll
    for (int md=0; md<4; md++) s1 = MFMA32(kfb[md], qf[md], s1);
  }
  __builtin_amdgcn_s_setprio(0);

  if (MASK){
    f32x16& sm = (NS==2) ? s1 : s0;
    #pragma unroll
    for (int r=0;r<16;r++){
      int kvl = (r&3) + 8*(r>>2) + 4*l1;
      if (kvl > l31) sm[r] = -3.0e38f;
    }
  }

  // ---- online softmax (log2 domain), lane-local + shfl_xor(32) combine ----
  float mx = -3.0e38f;
  #pragma unroll
  for (int r=0;r<16;r++) mx = fmaxf(mx, s0[r]);
  if (NS==2){
    #pragma unroll
    for (int r=0;r<16;r++) mx = fmaxf(mx, s1[r]);
  }
  mx = fmaxf(mx, __shfl_xor(mx, 32));
  if (!__all(mx - m_s <= 8.0f)){
    float mnew = fmaxf(m_s, mx);
    float alpha = __builtin_amdgcn_exp2f(m_s - mnew);
    l_s *= alpha;
    #pragma unroll
    for (int r=0;r<16;r++){ o0[r] *= alpha; o1[r] *= alpha; }
    m_s = mnew;
  }
  float rs = 0.f;
  #pragma unroll
  for (int r=0;r<16;r++){ s0[r] = __builtin_amdgcn_exp2f(s0[r]-m_s); rs += s0[r]; }
  if (NS==2){
    #pragma unroll
    for (int r=0;r<16;r++){ s1[r] = __builtin_amdgcn_exp2f(s1[r]-m_s); rs += s1[r]; }
  }
  rs += __shfl_xor(rs, 32);
  l_s += rs;

  // ---- P -> bf16 pairs; shfl_xor(32) + select builds B-fragments ----
  uint ru[16];
  #pragma unroll
  for (int j=0;j<8;j++) ru[j] = packbf2(s0[2*j], s0[2*j+1]);
  if (NS==2){
    #pragma unroll
    for (int j=0;j<8;j++) ru[8+j] = packbf2(s1[2*j], s1[2*j+1]);
  }
  union U4 { uint u[4]; bf16x8 v; };
  U4 fr[2*NS];
  #pragma unroll
  for (int j=0;j<NS;j++){
    uint px[8];
    #pragma unroll
    for (int k=0;k<8;k++) px[k] = xswap32(ru[8*j+k]);
    fr[2*j].u[0]   = l1 ? px[2]      : ru[8*j+0];
    fr[2*j].u[1]   = l1 ? px[3]      : ru[8*j+1];
    fr[2*j].u[2]   = l1 ? ru[8*j+2]  : px[0];
    fr[2*j].u[3]   = l1 ? ru[8*j+3]  : px[1];
    fr[2*j+1].u[0] = l1 ? px[6]      : ru[8*j+4];
    fr[2*j+1].u[1] = l1 ? px[7]      : ru[8*j+5];
    fr[2*j+1].u[2] = l1 ? ru[8*j+6]  : px[4];
    fr[2*j+1].u[3] = l1 ? ru[8*j+7]  : px[5];
  }

  // ---- PV: O^T[d][q] += V^T fragments x P ----
  __builtin_amdgcn_s_setprio(1);
  #pragma unroll
  for (int kc=0; kc<2*NS; kc++){
    o0 = MFMA32(vf0[kc], fr[kc].v, o0);
    o1 = MFMA32(vf1[kc], fr[kc].v, o1);
  }
  __builtin_amdgcn_s_setprio(0);
}

__device__ __forceinline__ void process_tile(
    int t, int par, int bh,
    const ushort* __restrict__ Q, const ushort* __restrict__ K,
    const ushort* __restrict__ VT, ushort* __restrict__ O,
    int l31, int l1)
{
  const size_t base  = (size_t)bh * SEQ * DH;
  const size_t vbase = (size_t)bh * DH * SEQ;
  const ushort* Kp = K + base;
  const ushort* Vp = VT + vbase;
  const int qbase = t*64 + par*32;

  bf16x8 qf[4];
  #pragma unroll
  for (int md=0; md<4; md++)
    qf[md] = *(const bf16x8*)&Q[base + (size_t)(qbase + l31)*DH + md*16 + l1*8];

  f32x16 o0 = ZERO16, o1 = ZERO16;
  float m_s = -3.0e38f, l_s = 0.f;

  for (int kt=0; kt<t; kt++)
    attn_iter<2,false>(Kp, Vp, kt*64, qf, l31, l1, o0, o1, m_s, l_s);
  if (par) attn_iter<2,true>(Kp, Vp, t*64, qf, l31, l1, o0, o1, m_s, l_s);
  else     attn_iter<1,true>(Kp, Vp, t*64, qf, l31, l1, o0, o1, m_s, l_s);

  float li = 1.0f / l_s;
  int b = bh >> 4, hh = bh & 15;
  int n = qbase + l31;
  ushort* orow = O + ((size_t)b*SEQ + n)*DIMD + hh*64;
  #pragma unroll
  for (int r=0;r<16;r++){
    int dl = (r&3) + 8*(r>>2) + 4*l1;
    orow[dl]    = f2bf(o0[r]*li);
    orow[32+dl] = f2bf(o1[r]*li);
  }
}

__global__ __launch_bounds__(256, 2) void attn_kernel(
    const ushort* __restrict__ Q, const ushort* __restrict__ K, const ushort* __restrict__ VT,
    ushort* __restrict__ O)
{
  int id = blockIdx.x;                  // 512 blocks
  int p  = id >> 6;                     // pair index 0..7 -> tiles {p, 15-p}
  int r  = id & 63;
  int bh = (r&7)*8 + (r>>3);            // XCD x serves bh in [8x, 8x+8)
  int tid = threadIdx.x, wi = tid>>6, lane = tid&63;
  int l31 = lane & 31, l1 = lane >> 5;
  int sel = (wi & 1) ^ (bh & 1);        // balance SIMD load across co-resident blocks
  int t   = sel ? (15-p) : p;
  int par = wi >> 1;
  process_tile(t, par, bh, Q, K, VT, O, l31, l1);
}

extern "C" void kernel_launch(void* const* d_in, const int* in_sizes, int n_in,
                              void* d_out, int out_size, void* d_ws, size_t ws_size,
                              hipStream_t stream)
{
  const float* x      = (const float*)d_in[0];
  const float* w_q    = (const float*)d_in[1];
  const float* w_k    = (const float*)d_in[2];
  const float* w_v    = (const float*)d_in[3];
  const float* w_o    = (const float*)d_in[4];
  const float* qparam = (const float*)d_in[5];
  char* ws = (char*)d_ws;
  const size_t MB = 1u<<20;
  ushort* xb  = (ushort*)(ws);             // 8MB; reused as attention output
  ushort* wqb = (ushort*)(ws + 8*MB);      // 2MB each
  ushort* wkb = (ushort*)(ws + 10*MB);
  ushort* wvb = (ushort*)(ws + 12*MB);
  ushort* wob = (ushort*)(ws + 14*MB);
  ushort* qd  = (ushort*)(ws + 16*MB);     // 8MB each
  ushort* kd  = (ushort*)(ws + 24*MB);
  ushort* vd  = (ushort*)(ws + 32*MB);     // V^T [bh][d][n], wo-colsum folded
  ushort* att = xb;
  float* part = (float*)(ws + 40*MB);      // 128KB scratch
  float* colsum = (float*)d_out + (out_size - 1024);  // overwritten by final GEMM

  prep_kernel<<<dim3(5664), dim3(256), 0, stream>>>(
      x, w_q, w_k, w_v, w_o, xb, wqb, wkb, wvb, wob, part);
  wo_csum_kernel<<<dim3(4), dim3(256), 0, stream>>>(part, colsum);
  gemm_fused_kernel<3><<<dim3(64,16), dim3(256), 0, stream>>>(
      xb, wqb, wkb, wvb, (void*)qd, (void*)kd, (void*)vd, qparam, colsum, DIMD);
  attn_kernel<<<dim3(512), dim3(256), 0, stream>>>(qd, kd, vd, att);
  gemm_fused_kernel<1><<<dim3(64,16), dim3(256), 0, stream>>>(
      att, wob, wob, wob, d_out, nullptr, nullptr, nullptr, nullptr, DIMD);
}